// Round 9
// baseline (372.198 us; speedup 1.0000x reference)
//
#include <hip/hip_runtime.h>
#include <hip/hip_bf16.h>

// Problem constants (fixed by the reference)
constexpr int BATCH  = 32;
constexpr int TIME   = 1024;
constexpr int IN_DIM = 512;
constexpr int HIDDEN = 512;

// ---------------- Fused GEMM + LIF scan ----------------
// R1-R8 finding: ANY standalone scan kernel pins at ~100us (~1.2 TB/s,
// ~1KB effective in-flight per block) across 6 structurally different
// designs (register prefetch, LDS-DMA strided/contiguous, relaxed flags,
// multi-producer). Rather than fight the plateau, eliminate it: fuse the
// scan into the GEMM. The 64 MB I_in write + 64 MB read disappear; the
// scan consumes GEMM chunks straight out of LDS, overlapped with compute.
//
// Structure: 256 blocks (1/CU), block = (b, 64-wide h-slice). 5 waves:
//   waves 0-3: GEMM  C[1024 x 64] = spikes[b][1024 x 512] @ W[512 x 64]
//              in 4 T-chunks of 256 (tile 256x64x16, 8x8 microtile,
//              reg-double-buffer staging: load kt+1 regs before compute kt
//              -- mandatory at 1 block/CU, no sibling blocks hide latency)
//   wave 4:    LIF scan of chunk c-1 from the 2-slot LDS ring while GEMM
//              computes chunk c; writes spikes straight to d_out.
// Sync: scan wave executes the IDENTICAL __syncthreads skeleton (65/chunk
// both paths -- counts must match exactly or hang); its 8-timestep slice
// per k-tile runs after the 2nd barrier, inside GEMM's ~2048-cyc compute
// window. Tail chunk scanned barrier-free after GEMM waves exit.
// VGPR lesson (R2): plain launch_bounds, never a min-occupancy cap.
constexpr int TC   = 256;              // timesteps per chunk
constexpr int NC   = TIME / TC;        // 4 chunks
constexpr int BK   = 16;               // k-tile
constexpr int NKT  = IN_DIM / BK;      // 32 k-tiles
constexpr int LDA2 = TC + 4;           // A^T in LDS, padded
constexpr int LDB2 = 64 + 4;           // B tile padded

__global__ __launch_bounds__(320) void fused_lif_kernel(
    const float* __restrict__ A,     // spikes [B, T, I]
    const float* __restrict__ Bw,    // W [I, H]
    const float* __restrict__ bias,  // [H]
    float* __restrict__ O)           // out [B, T, H]
{
    __shared__ __align__(16) float As[BK * LDA2];      // 16.6 KB
    __shared__ __align__(16) float Bs[BK * LDB2];      //  4.4 KB
    __shared__ __align__(16) float ring[2][TC * 64];   // 128 KB

    const int blk  = blockIdx.x;           // 0..255
    const int b    = blk >> 3;
    const int h0   = (blk & 7) * 64;
    const int wave = threadIdx.x >> 6;     // 0..4
    const int lane = threadIdx.x & 63;

    const float* Ab = A + (size_t)b * TIME * IN_DIM;   // [1024, 512]

    if (wave < 4) {
        // ================= GEMM waves =================
        const int tid = threadIdx.x;       // 0..255 here
        // A-tile loads: 4 float4/thread: rows ar+64q (0..255), cols ac..ac+3
        const int ar = tid >> 2;           // 0..63
        const int ac = (tid & 3) << 2;     // 0,4,8,12
        // B-tile: 1 float4/thread: row br (0..15), cols bc..bc+3 (0..60)
        const int br = tid >> 4;
        const int bc = (tid & 15) << 2;
        // fragment coords: row0 = t within chunk, col0 = h within 64
        const int row0 = wave * 64 + (lane >> 3) * 8;  // 0..248
        const int col0 = (lane & 7) * 8;               // 0..56

        float4 va[4], vb;
        auto load_tile = [&](int c, int kt) {
            const float* Ap = Ab + (size_t)(c * TC) * IN_DIM + kt * BK;
            #pragma unroll
            for (int q = 0; q < 4; ++q)
                va[q] = *reinterpret_cast<const float4*>(
                    Ap + (size_t)(ar + 64 * q) * IN_DIM + ac);
            vb = *reinterpret_cast<const float4*>(
                Bw + (size_t)(kt * BK + br) * HIDDEN + h0 + bc);
        };
        auto store_tile = [&]() {
            #pragma unroll
            for (int q = 0; q < 4; ++q) {
                As[(ac + 0) * LDA2 + ar + 64 * q] = va[q].x;
                As[(ac + 1) * LDA2 + ar + 64 * q] = va[q].y;
                As[(ac + 2) * LDA2 + ar + 64 * q] = va[q].z;
                As[(ac + 3) * LDA2 + ar + 64 * q] = va[q].w;
            }
            *reinterpret_cast<float4*>(&Bs[br * LDB2 + bc]) = vb;
        };

        #pragma unroll 1
        for (int c = 0; c < NC; ++c) {
            float acc[8][8];
            #pragma unroll
            for (int i = 0; i < 8; ++i)
                #pragma unroll
                for (int j = 0; j < 8; ++j) acc[i][j] = 0.0f;

            load_tile(c, 0);

            #pragma unroll 1
            for (int kt = 0; kt < NKT; ++kt) {
                __syncthreads();               // (A) prev compute done
                store_tile();                  // waits vmcnt for this kt's regs
                if (kt + 1 < NKT) load_tile(c, kt + 1);   // in flight thru compute
                __syncthreads();               // (B) staging visible

                #pragma unroll
                for (int kk = 0; kk < BK; ++kk) {
                    const float4 a0 = *reinterpret_cast<const float4*>(&As[kk * LDA2 + row0]);
                    const float4 a1 = *reinterpret_cast<const float4*>(&As[kk * LDA2 + row0 + 4]);
                    const float4 b0 = *reinterpret_cast<const float4*>(&Bs[kk * LDB2 + col0]);
                    const float4 b1 = *reinterpret_cast<const float4*>(&Bs[kk * LDB2 + col0 + 4]);
                    const float arr[8] = {a0.x, a0.y, a0.z, a0.w, a1.x, a1.y, a1.z, a1.w};
                    const float brr[8] = {b0.x, b0.y, b0.z, b0.w, b1.x, b1.y, b1.z, b1.w};
                    #pragma unroll
                    for (int i = 0; i < 8; ++i)
                        #pragma unroll
                        for (int j = 0; j < 8; ++j)
                            acc[i][j] = fmaf(arr[i], brr[j], acc[i][j]);
                }
            }

            // bias add (once, after full k=512 accumulation -- matches ref
            // rounding) + write chunk to ring slot c&1, t-major
            float* rp = ring[c & 1];
            #pragma unroll
            for (int i = 0; i < 8; ++i) {
                #pragma unroll
                for (int j = 0; j < 8; j += 4) {
                    float4 v;
                    v.x = __fadd_rn(acc[i][j + 0], bias[h0 + col0 + j + 0]);
                    v.y = __fadd_rn(acc[i][j + 1], bias[h0 + col0 + j + 1]);
                    v.z = __fadd_rn(acc[i][j + 2], bias[h0 + col0 + j + 2]);
                    v.w = __fadd_rn(acc[i][j + 3], bias[h0 + col0 + j + 3]);
                    *reinterpret_cast<float4*>(&rp[(row0 + i) * 64 + col0 + j]) = v;
                }
            }
            __syncthreads();                   // (C) ring[c&1] complete
        }
        // GEMM waves exit; scan wave has NO barriers after this point.
    } else {
        // ================= scan wave =================
        // exp(-0.05), exp(-0.2) correctly rounded fp32 (match np.exp)
        const float am = 0.95122942450071400910f;
        const float as = 0.81873075307798185867f;
        float v = 0.0f, s = 0.0f;
        float* o0 = O + (size_t)b * TIME * HIDDEN + h0 + lane;

        auto slice = [&](const float* rp, int tbase, int tglob) {
            float xb[8];
            #pragma unroll
            for (int u = 0; u < 8; ++u)
                xb[u] = rp[(tbase + u) * 64 + lane];
            float ob[8];
            #pragma unroll
            for (int u = 0; u < 8; ++u) {
                // separate mul/add roundings to match numpy (no FMA fusion)
                s = __fadd_rn(__fmul_rn(as, s), xb[u]);
                v = __fadd_rn(__fmul_rn(am, v), s);
                const float o = (v > 1.0f) ? 1.0f : 0.0f;
                v = __fsub_rn(v, o);
                ob[u] = o;
            }
            #pragma unroll
            for (int u = 0; u < 8; ++u)
                o0[(size_t)(tglob + u) * HIDDEN] = ob[u];
        };

        #pragma unroll 1
        for (int c = 0; c < NC; ++c) {
            const float* rp = ring[(c + 1) & 1];   // chunk c-1's slot
            #pragma unroll 1
            for (int kt = 0; kt < NKT; ++kt) {
                __syncthreads();               // matches (A)
                __syncthreads();               // matches (B)
                if (c > 0)                     // slice overlaps GEMM compute
                    slice(rp, kt * 8, (c - 1) * TC + kt * 8);
            }
            __syncthreads();                   // matches (C)
        }
        // tail: last chunk, barrier-free (GEMM waves have exited)
        const float* rp = ring[(NC - 1) & 1];
        #pragma unroll 1
        for (int kt = 0; kt < NKT; ++kt)
            slice(rp, kt * 8, (NC - 1) * TC + kt * 8);
    }
}

extern "C" void kernel_launch(void* const* d_in, const int* in_sizes, int n_in,
                              void* d_out, int out_size, void* d_ws, size_t ws_size,
                              hipStream_t stream) {
    const float* spikes = (const float*)d_in[0];   // [32, 1024, 512]
    const float* W      = (const float*)d_in[1];   // [512, 512]
    const float* bias   = (const float*)d_in[2];   // [512]
    float* out = (float*)d_out;                    // [32, 1024, 512]
    // d_ws unused: the I_in round-trip is gone.

    fused_lif_kernel<<<256, 320, 0, stream>>>(spikes, W, bias, out);
}

// Round 10
// 317.860 us; speedup vs baseline: 1.1709x; 1.1709x over previous
//
#include <hip/hip_runtime.h>
#include <hip/hip_bf16.h>

// Problem constants (fixed by the reference)
constexpr int BATCH  = 32;
constexpr int TIME   = 1024;
constexpr int IN_DIM = 512;
constexpr int HIDDEN = 512;

constexpr int GM = BATCH * TIME;   // 32768  (GEMM M)
constexpr int GN = HIDDEN;         // 512    (GEMM N)
constexpr int GK = IN_DIM;         // 512    (GEMM K)

// ---------------- Phase 1: fp32 SGEMM with bias ----------------
// 128x128x16, 256 threads, 8x8 microtile, BOTH operands via LDS. Best
// measured body across R1-R9 (R6/R7: 203us, VALUBusy 68%; LDS-read floor
// ~164us, FMA floor ~109us -> ~83% of perfect overlap). R9 fusion attempt:
// 1 block/CU killed TLP (VALUBusy 41%) -> fusion is structurally worse.
// KEEP THIS BODY VERBATIM.
constexpr int BM = 128;
constexpr int BN = 128;
constexpr int BK = 16;
constexpr int LDAs = BM + 4;   // padded (2-way LDS alias only = free)
constexpr int LDBs = BN + 4;

__global__ __launch_bounds__(256) void sgemm_bias_kernel(
    const float* __restrict__ A,     // [GM, GK]
    const float* __restrict__ B,     // [GK, GN]
    const float* __restrict__ bias,  // [GN]
    float* __restrict__ C)           // [GM, GN]
{
    __shared__ __align__(16) float As[BK * LDAs];
    __shared__ __align__(16) float Bs[BK * LDBs];

    const int tid = threadIdx.x;           // 0..255
    const int bm  = blockIdx.x * BM;       // M-tile (256): same-A blocks are
    const int bn  = blockIdx.y * BN;       // 256 apart -> same XCD (L2 reuse)

    const int w    = tid >> 6;
    const int lane = tid & 63;
    const int row0 = (w >> 1) * 64 + (lane >> 3) * 8;
    const int col0 = (w & 1)  * 64 + (lane & 7)  * 8;

    const int ar0 = tid >> 2;              // A row for quad 0 (0..63), +64
    const int ac  = (tid & 3) << 2;        // A col within K-tile (0..12)
    const int br0 = tid >> 5;              // B row for quad 0 (0..7), +8
    const int bc  = (tid & 31) << 2;       // B col within N-tile (0..124)

    float acc[8][8];
    #pragma unroll
    for (int i = 0; i < 8; ++i)
        #pragma unroll
        for (int j = 0; j < 8; ++j) acc[i][j] = 0.0f;

    #pragma unroll 1
    for (int k0 = 0; k0 < GK; k0 += BK) {
        float4 va0 = *reinterpret_cast<const float4*>(A + (size_t)(bm + ar0) * GK + k0 + ac);
        float4 va1 = *reinterpret_cast<const float4*>(A + (size_t)(bm + ar0 + 64) * GK + k0 + ac);
        float4 vb0 = *reinterpret_cast<const float4*>(B + (size_t)(k0 + br0) * GN + bn + bc);
        float4 vb1 = *reinterpret_cast<const float4*>(B + (size_t)(k0 + br0 + 8) * GN + bn + bc);

        __syncthreads();   // previous tile's compute done before overwrite

        As[(ac + 0) * LDAs + ar0] = va0.x;
        As[(ac + 1) * LDAs + ar0] = va0.y;
        As[(ac + 2) * LDAs + ar0] = va0.z;
        As[(ac + 3) * LDAs + ar0] = va0.w;
        As[(ac + 0) * LDAs + ar0 + 64] = va1.x;
        As[(ac + 1) * LDAs + ar0 + 64] = va1.y;
        As[(ac + 2) * LDAs + ar0 + 64] = va1.z;
        As[(ac + 3) * LDAs + ar0 + 64] = va1.w;
        *reinterpret_cast<float4*>(&Bs[br0 * LDBs + bc]) = vb0;
        *reinterpret_cast<float4*>(&Bs[(br0 + 8) * LDBs + bc]) = vb1;

        __syncthreads();

        #pragma unroll
        for (int kk = 0; kk < BK; ++kk) {
            const float4 a0 = *reinterpret_cast<const float4*>(&As[kk * LDAs + row0]);
            const float4 a1 = *reinterpret_cast<const float4*>(&As[kk * LDAs + row0 + 4]);
            const float4 b0 = *reinterpret_cast<const float4*>(&Bs[kk * LDBs + col0]);
            const float4 b1 = *reinterpret_cast<const float4*>(&Bs[kk * LDBs + col0 + 4]);
            const float arr[8] = {a0.x, a0.y, a0.z, a0.w, a1.x, a1.y, a1.z, a1.w};
            const float brr[8] = {b0.x, b0.y, b0.z, b0.w, b1.x, b1.y, b1.z, b1.w};
            #pragma unroll
            for (int i = 0; i < 8; ++i)
                #pragma unroll
                for (int j = 0; j < 8; ++j)
                    acc[i][j] = fmaf(arr[i], brr[j], acc[i][j]);
        }
    }

    // ---- epilogue: add bias (separate fp32 add, like numpy), store ----
    #pragma unroll
    for (int i = 0; i < 8; ++i) {
        const size_t r = (size_t)(bm + row0 + i);
        #pragma unroll
        for (int j = 0; j < 8; j += 4) {
            float4 v;
            v.x = __fadd_rn(acc[i][j + 0], bias[bn + col0 + j + 0]);
            v.y = __fadd_rn(acc[i][j + 1], bias[bn + col0 + j + 1]);
            v.z = __fadd_rn(acc[i][j + 2], bias[bn + col0 + j + 2]);
            v.w = __fadd_rn(acc[i][j + 3], bias[bn + col0 + j + 3]);
            *reinterpret_cast<float4*>(&C[r * GN + bn + col0 + j]) = v;
        }
    }
}

// ---------------- Phase 2: LIF scan v7 — chain + L2-warming prefetch ------
// Plateau diagnosis (R1-R8): every scan pinned at ~1.2 TB/s. R1's config
// makes it exact: 1 wave/CU x ~16 loads x 256B = 4KB in flight / ~900ns HBM
// latency = 4.5 GB/s/CU x 256 = 1.15 TB/s == measured. Address pattern is
// irrelevant (R8: contiguous == strided); DMA/producer paths never raised
// in-flight bytes. v7 raises in-flight bytes directly: 3 PREFETCH waves per
// block issue independent loads (3 x 32 x 256B = 24KB/block ~ 6MB chip-wide
// >= 5.7MB BW*latency product) purely to warm L2; the chain wave then hits
// L2 (~200cyc) and needs 4.5x less in-flight to stream. Prefetch is pure
// pacing -- zero correctness coupling (relaxed flag, <=96KB/block ahead,
// 24MB chip-wide < 32MB aggregate L2).
constexpr int CCH   = 32;              // timesteps per chunk
constexpr int CNCH  = TIME / CCH;      // 32 chunks
constexpr int AHEAD = 12;              // prefetch-ahead in chunks (8 KB each)

__global__ __launch_bounds__(256) void lif_scan_kernel(
    const float* __restrict__ I,   // [B, T, H]
    float* __restrict__ O)         // [B, T, H]
{
    __shared__ int progress;               // chain's current chunk (pacing only)

    const int blk  = blockIdx.x;           // 0..255
    const int b    = blk >> 3;
    const int h0   = (blk & 7) * 64;
    const int wave = threadIdx.x >> 6;
    const int lane = threadIdx.x & 63;
    const size_t base = (size_t)b * TIME * HIDDEN + h0 + lane;

    if (threadIdx.x == 0) progress = 0;
    __syncthreads();

    if (wave < 3) {
        // ---------- prefetch waves: warm L2, keep HBM queue full ----------
        const float* g0 = I + base;
        float acc = 0.0f;
        #pragma unroll 1
        for (int c = wave; c < CNCH; c += 3) {
            // throttle: stay <= AHEAD chunks in front of the chain
            while (__hip_atomic_load(&progress, __ATOMIC_RELAXED,
                                     __HIP_MEMORY_SCOPE_WORKGROUP) + AHEAD < c) { }
            const float* gp = g0 + (size_t)c * CCH * HIDDEN;
            float a0 = 0.f, a1 = 0.f, a2 = 0.f, a3 = 0.f;
            #pragma unroll
            for (int u = 0; u < CCH; u += 4) {   // 32 independent loads in flight
                a0 += gp[(size_t)(u + 0) * HIDDEN];
                a1 += gp[(size_t)(u + 1) * HIDDEN];
                a2 += gp[(size_t)(u + 2) * HIDDEN];
                a3 += gp[(size_t)(u + 3) * HIDDEN];
            }
            acc += (a0 + a1) + (a2 + a3);
        }
        asm volatile("" :: "v"(acc));      // keep the loads alive
    } else {
        // ---------- chain wave: the LIF recurrence, loads now L2-hot ------
        // exp(-0.05), exp(-0.2) correctly rounded fp32 (match np.exp)
        const float am = 0.95122942450071400910f;
        const float as = 0.81873075307798185867f;
        float v = 0.0f, s = 0.0f;
        const float* Ip = I + base;
        float*       Op = O + base;

        #pragma unroll 1
        for (int c = 0; c < CNCH; ++c) {
            float buf[CCH];
            #pragma unroll
            for (int u = 0; u < CCH; ++u)
                buf[u] = Ip[(size_t)(c * CCH + u) * HIDDEN];
            // publish early: loads issued; flag is pacing-only, not ordering
            __hip_atomic_store(&progress, c, __ATOMIC_RELAXED,
                               __HIP_MEMORY_SCOPE_WORKGROUP);
            float ob[CCH];
            #pragma unroll
            for (int u = 0; u < CCH; ++u) {
                // separate mul/add roundings to match numpy (no FMA fusion)
                s = __fadd_rn(__fmul_rn(as, s), buf[u]);
                v = __fadd_rn(__fmul_rn(am, v), s);
                const float o = (v > 1.0f) ? 1.0f : 0.0f;
                v = __fsub_rn(v, o);
                ob[u] = o;
            }
            #pragma unroll
            for (int u = 0; u < CCH; ++u)
                Op[(size_t)(c * CCH + u) * HIDDEN] = ob[u];
        }
    }
}

extern "C" void kernel_launch(void* const* d_in, const int* in_sizes, int n_in,
                              void* d_out, int out_size, void* d_ws, size_t ws_size,
                              hipStream_t stream) {
    const float* spikes = (const float*)d_in[0];   // [32, 1024, 512]
    const float* W      = (const float*)d_in[1];   // [512, 512]
    const float* bias   = (const float*)d_in[2];   // [512]
    float* out  = (float*)d_out;                   // [32, 1024, 512]
    float* I_in = (float*)d_ws;                    // 64 MiB scratch

    dim3 g1(GM / BM, GN / BN);                     // (256, 4)
    sgemm_bias_kernel<<<g1, 256, 0, stream>>>(spikes, W, bias, I_in);

    lif_scan_kernel<<<256, 256, 0, stream>>>(I_in, out);
}

// Round 11
// 304.446 us; speedup vs baseline: 1.2225x; 1.0441x over previous
//
#include <hip/hip_runtime.h>
#include <hip/hip_bf16.h>

// Problem constants (fixed by the reference)
constexpr int BATCH  = 32;
constexpr int TIME   = 1024;
constexpr int IN_DIM = 512;
constexpr int HIDDEN = 512;

constexpr int GM = BATCH * TIME;   // 32768  (GEMM M)
constexpr int GN = HIDDEN;         // 512    (GEMM N)
constexpr int GK = IN_DIM;         // 512    (GEMM K)

#define GLOBAL_AS __attribute__((address_space(1)))
#define LDS_AS    __attribute__((address_space(3)))

// s_waitcnt immediate: vmcnt[3:0]|expcnt(no-wait)|lgkmcnt(no-wait)|vmcnt[5:4]
#define WAITCNT_VMCNT(n) (((n) & 15) | (((n) >> 4) << 14) | (0x7 << 4) | (0xF << 8))

// ---------------- Phase 1: fp32 SGEMM with bias ----------------
// 128x128x16, 256 threads, 8x8 microtile, BOTH operands via LDS.
// Best measured GEMM across R1-R10 (203us, VALUBusy 68%, VGPR 52,
// 8 blocks/CU = max TLP). LDS-read floor ~164us; FMA floor ~109us.
// Failed variants for the record: (256,4) bound -> spill (R2, 950us);
// async-DMA pipeline -> VGPR 180, 1 blk/CU (R3, 385us); reg-double-buffer
// single barrier (R4, 252us); B-from-global -> L2-latency serialization
// (R5, 385us); fused with scan -> 1 blk/CU, VALUBusy 41% (R9, 318us).
// KEEP VERBATIM.
constexpr int BM = 128;
constexpr int BN = 128;
constexpr int BK = 16;
constexpr int LDAs = BM + 4;   // padded (2-way LDS alias only = free)
constexpr int LDBs = BN + 4;

__global__ __launch_bounds__(256) void sgemm_bias_kernel(
    const float* __restrict__ A,     // [GM, GK]
    const float* __restrict__ B,     // [GK, GN]
    const float* __restrict__ bias,  // [GN]
    float* __restrict__ C)           // [GM, GN]
{
    __shared__ __align__(16) float As[BK * LDAs];
    __shared__ __align__(16) float Bs[BK * LDBs];

    const int tid = threadIdx.x;           // 0..255
    const int bm  = blockIdx.x * BM;       // M-tile (256): same-A blocks are
    const int bn  = blockIdx.y * BN;       // 256 apart -> same XCD (L2 reuse)

    const int w    = tid >> 6;
    const int lane = tid & 63;
    const int row0 = (w >> 1) * 64 + (lane >> 3) * 8;
    const int col0 = (w & 1)  * 64 + (lane & 7)  * 8;

    const int ar0 = tid >> 2;              // A row for quad 0 (0..63), +64
    const int ac  = (tid & 3) << 2;        // A col within K-tile (0..12)
    const int br0 = tid >> 5;              // B row for quad 0 (0..7), +8
    const int bc  = (tid & 31) << 2;       // B col within N-tile (0..124)

    float acc[8][8];
    #pragma unroll
    for (int i = 0; i < 8; ++i)
        #pragma unroll
        for (int j = 0; j < 8; ++j) acc[i][j] = 0.0f;

    #pragma unroll 1
    for (int k0 = 0; k0 < GK; k0 += BK) {
        float4 va0 = *reinterpret_cast<const float4*>(A + (size_t)(bm + ar0) * GK + k0 + ac);
        float4 va1 = *reinterpret_cast<const float4*>(A + (size_t)(bm + ar0 + 64) * GK + k0 + ac);
        float4 vb0 = *reinterpret_cast<const float4*>(B + (size_t)(k0 + br0) * GN + bn + bc);
        float4 vb1 = *reinterpret_cast<const float4*>(B + (size_t)(k0 + br0 + 8) * GN + bn + bc);

        __syncthreads();   // previous tile's compute done before overwrite

        As[(ac + 0) * LDAs + ar0] = va0.x;
        As[(ac + 1) * LDAs + ar0] = va0.y;
        As[(ac + 2) * LDAs + ar0] = va0.z;
        As[(ac + 3) * LDAs + ar0] = va0.w;
        As[(ac + 0) * LDAs + ar0 + 64] = va1.x;
        As[(ac + 1) * LDAs + ar0 + 64] = va1.y;
        As[(ac + 2) * LDAs + ar0 + 64] = va1.z;
        As[(ac + 3) * LDAs + ar0 + 64] = va1.w;
        *reinterpret_cast<float4*>(&Bs[br0 * LDBs + bc]) = vb0;
        *reinterpret_cast<float4*>(&Bs[(br0 + 8) * LDBs + bc]) = vb1;

        __syncthreads();

        #pragma unroll
        for (int kk = 0; kk < BK; ++kk) {
            const float4 a0 = *reinterpret_cast<const float4*>(&As[kk * LDAs + row0]);
            const float4 a1 = *reinterpret_cast<const float4*>(&As[kk * LDAs + row0 + 4]);
            const float4 b0 = *reinterpret_cast<const float4*>(&Bs[kk * LDBs + col0]);
            const float4 b1 = *reinterpret_cast<const float4*>(&Bs[kk * LDBs + col0 + 4]);
            const float arr[8] = {a0.x, a0.y, a0.z, a0.w, a1.x, a1.y, a1.z, a1.w};
            const float brr[8] = {b0.x, b0.y, b0.z, b0.w, b1.x, b1.y, b1.z, b1.w};
            #pragma unroll
            for (int i = 0; i < 8; ++i)
                #pragma unroll
                for (int j = 0; j < 8; ++j)
                    acc[i][j] = fmaf(arr[i], brr[j], acc[i][j]);
        }
    }

    // ---- epilogue: add bias (separate fp32 add, like numpy), store ----
    #pragma unroll
    for (int i = 0; i < 8; ++i) {
        const size_t r = (size_t)(bm + row0 + i);
        #pragma unroll
        for (int j = 0; j < 8; j += 4) {
            float4 v;
            v.x = __fadd_rn(acc[i][j + 0], bias[bn + col0 + j + 0]);
            v.y = __fadd_rn(acc[i][j + 1], bias[bn + col0 + j + 1]);
            v.z = __fadd_rn(acc[i][j + 2], bias[bn + col0 + j + 2]);
            v.w = __fadd_rn(acc[i][j + 3], bias[bn + col0 + j + 3]);
            *reinterpret_cast<float4*>(&C[r * GN + bn + col0 + j]) = v;
        }
    }
}

// ---------------- Phase 2: LIF scan — R3 config VERBATIM ----------------
// Empirical champion: 86.9us (R3), vs 102-115us for every "improved"
// successor (width-16 DMA, relaxed flags, multi-producer, contiguous
// layout, L2-warming prefetch -- R4..R10 all regressed or tied). All my
// mechanistic theories for the plateau failed; this exact config is the
// best measured point in 7 designs. DO NOT "fix" it again: width-4 DMA,
// 32 DMAs/chunk, vmcnt(32) retirement, 128KB ring, RELEASE atomics.
constexpr int SCH    = 32;                 // timesteps per chunk
constexpr int NCHK   = TIME / SCH;         // 32 chunks
constexpr int RING_T = 512;                // ring capacity in timesteps
constexpr int RINGC  = RING_T / SCH;       // 16 ring chunks

__global__ __launch_bounds__(128) void lif_scan_kernel(
    const float* __restrict__ I,   // [B, T, H]
    float* __restrict__ O)         // [B, T, H]
{
    __shared__ float ring[RING_T * 64];    // 128 KB
    __shared__ int prod_c;                 // chunks fully landed in LDS
    __shared__ int cons_c;                 // chunks consumed

    const int blk  = blockIdx.x;           // 0..255
    const int b    = blk >> 3;             // 8 blocks per batch row
    const int h0   = (blk & 7) * 64;
    const int wave = threadIdx.x >> 6;
    const int lane = threadIdx.x & 63;
    const size_t base = (size_t)b * TIME * HIDDEN + h0;

    if (threadIdx.x == 0) { prod_c = 0; cons_c = 0; }
    __syncthreads();

    if (wave == 0) {
        // ---------------- producer ----------------
        const float* g0 = I + base + lane;
        #pragma unroll 1
        for (int c = 0; c < NCHK; ++c) {
            if (c >= RINGC) {   // backpressure: don't overwrite live slot
                while (__hip_atomic_load(&cons_c, __ATOMIC_ACQUIRE,
                                         __HIP_MEMORY_SCOPE_WORKGROUP)
                       <= c - RINGC) { }
            }
            const int slot = (c & (RINGC - 1)) * SCH;
            #pragma unroll
            for (int u = 0; u < SCH; ++u) {
                const int t = c * SCH + u;
                __builtin_amdgcn_global_load_lds(
                    (GLOBAL_AS const void*)(g0 + (size_t)t * HIDDEN),
                    (LDS_AS void*)&ring[(slot + u) * 64], 4, 0, 0);
            }
            // all but the newest 32 loads have landed => chunks <= c-1 done
            __builtin_amdgcn_s_waitcnt(WAITCNT_VMCNT(32));
            __hip_atomic_store(&prod_c, c, __ATOMIC_RELEASE,
                               __HIP_MEMORY_SCOPE_WORKGROUP);
        }
        __builtin_amdgcn_s_waitcnt(WAITCNT_VMCNT(0));
        __hip_atomic_store(&prod_c, NCHK, __ATOMIC_RELEASE,
                           __HIP_MEMORY_SCOPE_WORKGROUP);
    } else {
        // ---------------- consumer ----------------
        // exp(-0.05), exp(-0.2) correctly rounded fp32 (match np.exp)
        const float am = 0.95122942450071400910f;
        const float as = 0.81873075307798185867f;
        float v = 0.0f, s = 0.0f;
        float* o0 = O + base + lane;

        #pragma unroll 1
        for (int c = 0; c < NCHK; ++c) {
            while (__hip_atomic_load(&prod_c, __ATOMIC_ACQUIRE,
                                     __HIP_MEMORY_SCOPE_WORKGROUP) < c + 1) { }
            const int slot = (c & (RINGC - 1)) * SCH;
            float ob[SCH];
            #pragma unroll
            for (int u = 0; u < SCH; ++u) {
                const float x = ring[(slot + u) * 64 + lane];
                // separate mul/add roundings to match numpy (no FMA fusion)
                s = __fadd_rn(__fmul_rn(as, s), x);
                v = __fadd_rn(__fmul_rn(am, v), s);
                const float o = (v > 1.0f) ? 1.0f : 0.0f;
                v = __fsub_rn(v, o);
                ob[u] = o;
            }
            #pragma unroll
            for (int u = 0; u < SCH; ++u)
                o0[(size_t)(c * SCH + u) * HIDDEN] = ob[u];
            __hip_atomic_store(&cons_c, c + 1, __ATOMIC_RELEASE,
                               __HIP_MEMORY_SCOPE_WORKGROUP);
        }
    }
}

extern "C" void kernel_launch(void* const* d_in, const int* in_sizes, int n_in,
                              void* d_out, int out_size, void* d_ws, size_t ws_size,
                              hipStream_t stream) {
    const float* spikes = (const float*)d_in[0];   // [32, 1024, 512]
    const float* W      = (const float*)d_in[1];   // [512, 512]
    const float* bias   = (const float*)d_in[2];   // [512]
    float* out  = (float*)d_out;                   // [32, 1024, 512]
    float* I_in = (float*)d_ws;                    // 64 MiB scratch

    dim3 g1(GM / BM, GN / BN);                     // (256, 4)
    sgemm_bias_kernel<<<g1, 256, 0, stream>>>(spikes, W, bias, I_in);

    lif_scan_kernel<<<BATCH * HIDDEN / 64, 128, 0, stream>>>(I_in, out);
}